// Round 6
// baseline (217.258 us; speedup 1.0000x reference)
//
#include <hip/hip_runtime.h>
#include <hip/hip_bf16.h>

#define N_TOK 4096
#define D_DIM 512
#define E_NUM 8
#define H_DIM 2048
#define RB_NUM 256   // router blocks (16 tokens each)
#define TP_NUM 8704  // transpose tiles (64x32): 4096 wg + 4096 wu + 512 wd

typedef __attribute__((ext_vector_type(8))) short short8;
typedef __attribute__((ext_vector_type(4))) float f32x4;

__device__ inline short f2bs(float f) {
  __hip_bfloat16 h = __float2bfloat16(f);
  return *reinterpret_cast<short*>(&h);
}

// async global->LDS, 16 B per lane; lds dest is wave-uniform base + lane*16
__device__ inline void llds16(const short* g, short* l) {
  __builtin_amdgcn_global_load_lds(
      (const __attribute__((address_space(1))) void*)g,
      (__attribute__((address_space(3))) void*)l, 16, 0, 0);
}

// ---------- fused prep+router ----------
// blocks [0,256): router (16 tokens each, 16 lanes/token)
// blocks [256, 256+8704): 64r x 32c transpose tiles (wg/wu/wd)
// load phase: float4 (16 B/lane, 2 rounds); pack phase: round-0 proven scalar
__global__ void __launch_bounds__(256) prep_router_kernel(
    const float* __restrict__ wg, const float* __restrict__ wu,
    const float* __restrict__ wd, const float* __restrict__ x,
    const float* __restrict__ wr, short* __restrict__ wgb,
    short* __restrict__ wub, short* __restrict__ wdb, short* __restrict__ xb,
    int* __restrict__ cnt_blk, int* __restrict__ tok_bkt,
    float* __restrict__ p_bkt, float* __restrict__ psum_blk) {
  int u = blockIdx.x;
  int tid = threadIdx.x;

  if (u >= RB_NUM) {
    // ---- 64r x 32c transpose-convert, int-packed bf16 writes ----
    __shared__ float tbuf[64][33];
    int v = u - RB_NUM;
    const float* in;
    short* op;
    int R, C, c0, r0;
    if (v < 8192) {
      in = (v < 4096) ? wg : wu;
      op = (v < 4096) ? wgb : wub;
      int w = v & 4095;
      R = D_DIM; C = E_NUM * H_DIM;
      c0 = (w & 511) * 32; r0 = (w >> 9) * 64;
    } else {
      in = wd; op = wdb;
      int w = v - 8192;
      R = H_DIM; C = D_DIM;
      c0 = (w & 15) * 32; r0 = (w >> 4) * 64;
    }
    // load phase: float4 per lane; covers rows 0..63, cols 0..31
    int cx = tid & 7, ry = tid >> 3;  // cx: float4-col 0..7, ry: row 0..31
#pragma unroll
    for (int p = 0; p < 2; ++p) {
      int row = ry + 32 * p;
      float4 vv = *(const float4*)&in[(size_t)(r0 + row) * C + c0 + cx * 4];
      tbuf[row][cx * 4 + 0] = vv.x;
      tbuf[row][cx * 4 + 1] = vv.y;
      tbuf[row][cx * 4 + 2] = vv.z;
      tbuf[row][cx * 4 + 3] = vv.w;
    }
    __syncthreads();
    // pack phase: proven round-0 code (unchanged)
    int tx = tid & 31, ty = tid >> 5;
#pragma unroll
    for (int i = 0; i < 4; ++i) {
      int cl = ty + 8 * i;
      unsigned lo = (unsigned short)f2bs(tbuf[2 * tx][cl]);
      unsigned hi = (unsigned short)f2bs(tbuf[2 * tx + 1][cl]);
      ((int*)op)[(((size_t)(c0 + cl) * R) + r0) / 2 + tx] = (int)(lo | (hi << 16));
    }
    return;
  }

  // ---- router part: 16 tokens, 16 lanes per token ----
  __shared__ float wr_t[E_NUM * D_DIM];  // [e][d], 16 KB
  __shared__ int h_cnt[E_NUM];
  __shared__ float psh[E_NUM];
  int rb = u;
  for (int i = tid; i < D_DIM * E_NUM; i += 256)
    wr_t[(i & 7) * D_DIM + (i >> 3)] = wr[i];  // wr is [d][e]
  if (tid < E_NUM) { h_cnt[tid] = 0; psh[tid] = 0.f; }
  __syncthreads();

  int r = tid >> 4, pp = tid & 15;
  int t = rb * 16 + r;
  const float* xr0 = x + (size_t)t * D_DIM;
  short* xw0 = xb + (size_t)t * D_DIM;
  float acc[8] = {0, 0, 0, 0, 0, 0, 0, 0};
#pragma unroll
  for (int j = 0; j < 8; ++j) {
    int d = j * 64 + pp * 4;  // 16 lanes cover 64 consecutive floats
    float4 xv = *(const float4*)(xr0 + d);
    short4 o;
    o.x = f2bs(xv.x); o.y = f2bs(xv.y); o.z = f2bs(xv.z); o.w = f2bs(xv.w);
    *(short4*)(xw0 + d) = o;
#pragma unroll
    for (int e = 0; e < 8; ++e) {
      float4 w = *(const float4*)&wr_t[e * D_DIM + d];
      acc[e] += xv.x * w.x + xv.y * w.y + xv.z * w.z + xv.w * w.w;
    }
  }
#pragma unroll
  for (int e = 0; e < 8; ++e) {
    acc[e] += __shfl_xor(acc[e], 1);
    acc[e] += __shfl_xor(acc[e], 2);
    acc[e] += __shfl_xor(acc[e], 4);
    acc[e] += __shfl_xor(acc[e], 8);
  }

  if (pp == 0) {
    float m = acc[0];
#pragma unroll
    for (int e = 1; e < 8; ++e) m = fmaxf(m, acc[e]);
    float p[8], s = 0.f;
#pragma unroll
    for (int e = 0; e < 8; ++e) { p[e] = expf(acc[e] - m); s += p[e]; }
    float inv = 1.f / s;
#pragma unroll
    for (int e = 0; e < 8; ++e) {
      p[e] *= inv;
      atomicAdd(&psh[e], p[e]);  // LDS scope
    }
    int i0 = 0;
#pragma unroll
    for (int e = 1; e < 8; ++e) if (p[e] > p[i0]) i0 = e;
    int i1 = (i0 == 0) ? 1 : 0;
#pragma unroll
    for (int e = 0; e < 8; ++e) if (e != i0 && p[e] > p[i1]) i1 = e;
    float ps = p[i0] + p[i1] + 1e-10f;
    float q0 = p[i0] / ps, q1 = p[i1] / ps;
    int l0 = atomicAdd(&h_cnt[i0], 1);  // LDS scope
    int l1 = atomicAdd(&h_cnt[i1], 1);
    tok_bkt[i0 * (RB_NUM * 16) + rb * 16 + l0] = t * 2 + 0;
    p_bkt[i0 * (RB_NUM * 16) + rb * 16 + l0] = q0;
    tok_bkt[i1 * (RB_NUM * 16) + rb * 16 + l1] = t * 2 + 1;
    p_bkt[i1 * (RB_NUM * 16) + rb * 16 + l1] = q1;
  }
  __syncthreads();
  if (tid < E_NUM) {
    cnt_blk[rb * 8 + tid] = h_cnt[tid];   // plain stores, fully owned
    psum_blk[rb * 8 + tid] = psh[tid];
  }
}

// ---------- route pack: 128 blocks = 8 experts x 16 rb-chunks ----------
__global__ void __launch_bounds__(256) route_pack_kernel(
    const int* __restrict__ cnt_blk, const int* __restrict__ tok_bkt,
    const float* __restrict__ p_bkt, int* __restrict__ dense_tok,
    float* __restrict__ dense_p, int* __restrict__ n_tot) {
  int e = blockIdx.x >> 4;
  int chunk = blockIdx.x & 15;
  int tid = threadIdx.x, lane = tid & 63, wid = tid >> 6;
  __shared__ int wsum[4];
  __shared__ int s_excl[16];
  __shared__ int s_cnt[16];
  int c = cnt_blk[tid * 8 + e];
  int inc = c;
#pragma unroll
  for (int ofs = 1; ofs < 64; ofs <<= 1) {
    int v = __shfl_up(inc, ofs);
    if (lane >= ofs) inc += v;
  }
  if (lane == 63) wsum[wid] = inc;
  __syncthreads();
  int pre = 0;
#pragma unroll
  for (int w = 0; w < 4; ++w) pre += (w < wid) ? wsum[w] : 0;
  int excl = inc + pre - c;
  if ((tid >> 4) == chunk) {
    s_excl[tid & 15] = excl;
    s_cnt[tid & 15] = c;
  }
  if (chunk == 0 && tid == 255) n_tot[e] = inc + pre;
  __syncthreads();
  int rbl = tid >> 4, i = tid & 15;
  int rb = chunk * 16 + rbl;
  if (i < s_cnt[rbl]) {
    int src = e * (RB_NUM * 16) + rb * 16 + i;
    int dst = e * N_TOK + s_excl[rbl] + i;
    dense_tok[dst] = tok_bkt[src];
    dense_p[dst] = p_bkt[src];
  }
}

// ---------- grouped gate/up GEMM (256 tok x 128 h tile, G+U fused) ----------
// 512 threads / 8 waves (4m x 2n); same proven 2-barrier inner loop & swizzle.
// 528 active blocks -> single residency round at 2 blocks/CU, 16 waves/CU.
__global__ void __launch_bounds__(512, 2) moe_gateup_kernel(
    const short* __restrict__ xb, const short* __restrict__ wg,
    const short* __restrict__ wu, const int* __restrict__ dense_tok,
    const float* __restrict__ dense_p, const int* __restrict__ n_tot,
    const float* __restrict__ psum_blk, short* __restrict__ act,
    float* __restrict__ out_loss) {
  int e = blockIdx.z;
  int tid = threadIdx.x;

  if (e == 8) {  // load-balance loss
    if (blockIdx.x || blockIdx.y) return;
    __shared__ float sums[8];
    if (tid < 8) sums[tid] = 0.f;
    __syncthreads();
    if (tid < 256) {
#pragma unroll
      for (int ee = 0; ee < 8; ++ee)
        atomicAdd(&sums[ee], psum_blk[tid * 8 + ee]);
    }
    __syncthreads();
    if (tid == 0) {
      float lb = 0.f;
#pragma unroll
      for (int ee = 0; ee < 8; ++ee) {
        float pe = sums[ee] / (float)N_TOK;
        lb += pe * logf(pe * 8.f + 1e-10f);
      }
      out_loss[0] = 8.f * lb;
    }
    return;
  }

  int n_e = n_tot[e];
  int rt = blockIdx.y;
  if (rt * 256 >= n_e) return;  // uniform early exit, one scalar load
  int h0 = blockIdx.x * 128;

  __shared__ __align__(16) short As[256 * 64];    // 32 KB
  __shared__ __align__(16) short Bgs[128 * 64];   // 16 KB
  __shared__ __align__(16) short Bus[128 * 64];   // 16 KB
  __shared__ int s_row[256];
  __shared__ float s_pr[256];

  int lane = tid & 63, wid = tid >> 6;  // wid 0..7

  if (tid < 256) {
    int r = rt * 256 + tid;
    int srow = -1;
    float spr = 0.f;
    if (r < n_e) {
      srow = dense_tok[e * N_TOK + r];
      spr = dense_p[e * N_TOK + r];
    }
    s_row[tid] = srow;
    s_pr[tid] = spr;
  }
  __syncthreads();

  int cg = (lane & 7) ^ (lane >> 3);  // swizzled global chunk for this lane
  // staging: wave w stages A rows [w*32, w*32+32); waves 0-3 stage Bg rows
  // [w*32..), waves 4-7 stage Bu rows [(w-4)*32..). 8 llds16 per wave per kt.
  const short* baseA[4];
  const short* baseB[4];
#pragma unroll
  for (int jj = 0; jj < 4; ++jj) {
    int r = wid * 32 + jj * 8 + (lane >> 3);
    int row = s_row[r];
    int t = (row < 0) ? 0 : (row >> 1);
    baseA[jj] = xb + (size_t)t * D_DIM + cg * 8;
  }
  short* ldsB = ((wid < 4) ? Bgs : Bus) + (wid & 3) * 2048;
  {
    const short* wB = ((wid < 4) ? wg : wu) + (size_t)e * H_DIM * D_DIM;
#pragma unroll
    for (int jj = 0; jj < 4; ++jj) {
      int h = h0 + (wid & 3) * 32 + jj * 8 + (lane >> 3);
      baseB[jj] = wB + (size_t)h * D_DIM + cg * 8;
    }
  }

  int ml = lane & 15, quad = lane >> 4;
  int mw = wid & 3, nw = wid >> 2;   // compute tile: 64 tok x 64 h per wave
  int m0w = mw * 64, n0w = nw * 64;
  f32x4 accG[4][4], accU[4][4];
#pragma unroll
  for (int mf = 0; mf < 4; ++mf)
#pragma unroll
    for (int nf = 0; nf < 4; ++nf) {
      accG[mf][nf] = (f32x4){0, 0, 0, 0};
      accU[mf][nf] = (f32x4){0, 0, 0, 0};
    }

  for (int kt = 0; kt < D_DIM / 64; ++kt) {
    int kb = kt * 64;
#pragma unroll
    for (int jj = 0; jj < 4; ++jj) {
      llds16(baseA[jj] + kb, As + wid * 2048 + jj * 512);
      llds16(baseB[jj] + kb, ldsB + jj * 512);
    }
    __syncthreads();
#pragma unroll
    for (int ks = 0; ks < 2; ++ks) {
      int cs = ((quad + ks * 4) ^ (ml & 7)) * 8;
      short8 a[4], bg[4], bu[4];
#pragma unroll
      for (int mf = 0; mf < 4; ++mf)
        a[mf] = *(const short8*)&As[(m0w + mf * 16 + ml) * 64 + cs];
#pragma unroll
      for (int nf = 0; nf < 4; ++nf) {
        bg[nf] = *(const short8*)&Bgs[(n0w + nf * 16 + ml) * 64 + cs];
        bu[nf] = *(const short8*)&Bus[(n0w + nf * 16 + ml) * 64 + cs];
      }
#pragma unroll
      for (int mf = 0; mf < 4; ++mf)
#pragma unroll
        for (int nf = 0; nf < 4; ++nf) {
          accG[mf][nf] = __builtin_amdgcn_mfma_f32_16x16x32_bf16(a[mf], bg[nf], accG[mf][nf], 0, 0, 0);
          accU[mf][nf] = __builtin_amdgcn_mfma_f32_16x16x32_bf16(a[mf], bu[nf], accU[mf][nf], 0, 0, 0);
        }
    }
    __syncthreads();
  }

#pragma unroll
  for (int mf = 0; mf < 4; ++mf)
#pragma unroll
    for (int r = 0; r < 4; ++r) {
      int rl = m0w + mf * 16 + quad * 4 + r;
      int arow = s_row[rl];
      if (arow >= 0) {
        float pr = s_pr[rl];
#pragma unroll
        for (int nf = 0; nf < 4; ++nf) {
          float g = accG[mf][nf][r], u = accU[mf][nf][r];
          float val = pr * (g / (1.f + __expf(-g))) * u;
          act[(size_t)arow * H_DIM + h0 + n0w + nf * 16 + ml] = f2bs(val);
        }
      }
    }
}

// ---------- down GEMM: partial[ksb][t][d] = act-slice @ wd ----------
// 128x128 tile, Ksplit=4 over blockIdx.z; per barrier-pair stage BOTH act
// slots + ONE shared wd chunk (48 KB, 3 blocks/CU) and run 64 MFMA/wave.
__global__ void __launch_bounds__(256, 3) down_kernel(
    const short* __restrict__ act, const short* __restrict__ wd,
    float* __restrict__ partial) {
  __shared__ __align__(16) short As0[128 * 64];  // 16 KB (slot 0)
  __shared__ __align__(16) short As1[128 * 64];  // 16 KB (slot 1)
  __shared__ __align__(16) short Bs[128 * 64];   // 16 KB
  int d0 = blockIdx.x * 128;
  int t0 = blockIdx.y * 128;
  int ksb = blockIdx.z;  // h-chunks [ksb*8, ksb*8+8)
  int tid = threadIdx.x, lane = tid & 63, wid = tid >> 6;
  int cg = (lane & 7) ^ (lane >> 3);

  const short* baseA[4];
  const short* baseB[4];
#pragma unroll
  for (int jj = 0; jj < 4; ++jj) {
    int r = wid * 32 + jj * 8 + (lane >> 3);
    baseA[jj] = act + (size_t)(2 * (t0 + r)) * H_DIM + cg * 8;
    int d = d0 + wid * 32 + jj * 8 + (lane >> 3);
    baseB[jj] = wd + (size_t)d * H_DIM + cg * 8;
  }

  int ml = lane & 15, quad = lane >> 4;
  int m0w = (wid & 1) * 64, n0w = (wid >> 1) * 64;
  f32x4 acc[4][4];
#pragma unroll
  for (int mf = 0; mf < 4; ++mf)
#pragma unroll
    for (int nf = 0; nf < 4; ++nf) acc[mf][nf] = (f32x4){0, 0, 0, 0};

  for (int j = 0; j < 8; ++j) {
    int hb = (ksb * 8 + j) * 64;
#pragma unroll
    for (int jj = 0; jj < 4; ++jj) {
      llds16(baseA[jj] + hb, As0 + wid * 2048 + jj * 512);
      llds16(baseA[jj] + H_DIM + hb, As1 + wid * 2048 + jj * 512);
      llds16(baseB[jj] + hb, Bs + wid * 2048 + jj * 512);
    }
    __syncthreads();
#pragma unroll
    for (int s = 0; s < 2; ++s) {
      const short* Asl = s ? As1 : As0;
#pragma unroll
      for (int ks = 0; ks < 2; ++ks) {
        int cs = ((quad + ks * 4) ^ (ml & 7)) * 8;
        short8 a[4], b[4];
#pragma unroll
        for (int mf = 0; mf < 4; ++mf)
          a[mf] = *(const short8*)&Asl[(m0w + mf * 16 + ml) * 64 + cs];
#pragma unroll
        for (int nf = 0; nf < 4; ++nf)
          b[nf] = *(const short8*)&Bs[(n0w + nf * 16 + ml) * 64 + cs];
#pragma unroll
        for (int mf = 0; mf < 4; ++mf)
#pragma unroll
          for (int nf = 0; nf < 4; ++nf)
            acc[mf][nf] = __builtin_amdgcn_mfma_f32_16x16x32_bf16(a[mf], b[nf], acc[mf][nf], 0, 0, 0);
      }
    }
    __syncthreads();
  }

  float* pout = partial + (size_t)ksb * N_TOK * D_DIM;
#pragma unroll
  for (int mf = 0; mf < 4; ++mf)
#pragma unroll
    for (int r = 0; r < 4; ++r) {
      int t = t0 + m0w + mf * 16 + quad * 4 + r;
#pragma unroll
      for (int nf = 0; nf < 4; ++nf)
        pout[(size_t)t * D_DIM + d0 + n0w + nf * 16 + ml] = acc[mf][nf][r];
    }
}

// ---------- split-K reduce: out = sum of 4 partials ----------
__global__ void __launch_bounds__(256) reduce_kernel(
    const float* __restrict__ partial, float* __restrict__ out) {
  int i = blockIdx.x * 256 + threadIdx.x;  // float4 index
  const int Q = N_TOK * D_DIM / 4;
  const float4* p = (const float4*)partial;
  float4 a = p[i], b = p[i + Q], c = p[i + 2 * Q], d = p[i + 3 * Q];
  float4 r = {a.x + b.x + c.x + d.x, a.y + b.y + c.y + d.y,
              a.z + b.z + c.z + d.z, a.w + b.w + c.w + d.w};
  ((float4*)out)[i] = r;
}

extern "C" void kernel_launch(void* const* d_in, const int* in_sizes, int n_in,
                              void* d_out, int out_size, void* d_ws, size_t ws_size,
                              hipStream_t stream) {
  const float* x = (const float*)d_in[0];
  const float* wr = (const float*)d_in[1];
  const float* wg = (const float*)d_in[2];
  const float* wu = (const float*)d_in[3];
  const float* wd = (const float*)d_in[4];
  float* out = (float*)d_out;

  char* ws = (char*)d_ws;
  size_t off = 0;
  auto alloc = [&](size_t bytes) {
    char* p = ws + off;
    off += (bytes + 255) & ~(size_t)255;
    return p;
  };
  short* xb = (short*)alloc((size_t)N_TOK * D_DIM * 2);
  short* wgb = (short*)alloc((size_t)E_NUM * H_DIM * D_DIM * 2);  // [e*H+h][d]
  short* wub = (short*)alloc((size_t)E_NUM * H_DIM * D_DIM * 2);
  short* wdb = (short*)alloc((size_t)D_DIM * H_DIM * 2);          // [d][h]
  short* act = (short*)alloc((size_t)N_TOK * 2 * H_DIM * 2);      // [2t+slot][H]
  float* partial = (float*)alloc((size_t)4 * N_TOK * D_DIM * 4);  // split-K partials
  int* cnt_blk = (int*)alloc((size_t)RB_NUM * E_NUM * 4);
  int* tok_bkt = (int*)alloc((size_t)E_NUM * RB_NUM * 16 * 4);
  float* p_bkt = (float*)alloc((size_t)E_NUM * RB_NUM * 16 * 4);
  float* psum_blk = (float*)alloc((size_t)RB_NUM * E_NUM * 4);
  int* dense_tok = (int*)alloc((size_t)E_NUM * N_TOK * 4);
  float* dense_p = (float*)alloc((size_t)E_NUM * N_TOK * 4);
  int* n_tot = (int*)alloc((size_t)E_NUM * 4);

  prep_router_kernel<<<RB_NUM + TP_NUM, 256, 0, stream>>>(
      wg, wu, wd, x, wr, wgb, wub, wdb, xb, cnt_blk, tok_bkt, p_bkt, psum_blk);
  route_pack_kernel<<<E_NUM * 16, 256, 0, stream>>>(
      cnt_blk, tok_bkt, p_bkt, dense_tok, dense_p, n_tot);
  moe_gateup_kernel<<<dim3(H_DIM / 128, N_TOK / 256, E_NUM + 1), 512, 0, stream>>>(
      xb, wgb, wub, dense_tok, dense_p, n_tot, psum_blk, act,
      out + (size_t)N_TOK * D_DIM);
  down_kernel<<<dim3(D_DIM / 128, N_TOK / 128, 4), 256, 0, stream>>>(
      act, wdb, partial);
  reduce_kernel<<<N_TOK * D_DIM / 4 / 256, 256, 0, stream>>>(partial, out);
}

// Round 7
// 196.427 us; speedup vs baseline: 1.1060x; 1.1060x over previous
//
#include <hip/hip_runtime.h>
#include <hip/hip_bf16.h>

#define N_TOK 4096
#define D_DIM 512
#define E_NUM 8
#define H_DIM 2048
#define RB_NUM 256   // router blocks (16 tokens each)
#define TP_NUM 8704  // transpose tiles (64x32): 4096 wg + 4096 wu + 512 wd

typedef __attribute__((ext_vector_type(8))) short short8;
typedef __attribute__((ext_vector_type(4))) float f32x4;

__device__ inline short f2bs(float f) {
  __hip_bfloat16 h = __float2bfloat16(f);
  return *reinterpret_cast<short*>(&h);
}

// async global->LDS, 16 B per lane; lds dest is wave-uniform base + lane*16
__device__ inline void llds16(const short* g, short* l) {
  __builtin_amdgcn_global_load_lds(
      (const __attribute__((address_space(1))) void*)g,
      (__attribute__((address_space(3))) void*)l, 16, 0, 0);
}

// ---------- fused prep+router ----------
// blocks [0,256): router (16 tokens each, 16 lanes/token)
// blocks [256, 256+8704): 64r x 32c transpose tiles (wg/wu/wd)
// load phase: float4 (16 B/lane, 2 rounds); pack phase: round-0 proven scalar
__global__ void __launch_bounds__(256) prep_router_kernel(
    const float* __restrict__ wg, const float* __restrict__ wu,
    const float* __restrict__ wd, const float* __restrict__ x,
    const float* __restrict__ wr, short* __restrict__ wgb,
    short* __restrict__ wub, short* __restrict__ wdb, short* __restrict__ xb,
    int* __restrict__ cnt_blk, int* __restrict__ tok_bkt,
    float* __restrict__ p_bkt, float* __restrict__ psum_blk) {
  int u = blockIdx.x;
  int tid = threadIdx.x;

  if (u >= RB_NUM) {
    // ---- 64r x 32c transpose-convert, int-packed bf16 writes ----
    __shared__ float tbuf[64][33];
    int v = u - RB_NUM;
    const float* in;
    short* op;
    int R, C, c0, r0;
    if (v < 8192) {
      in = (v < 4096) ? wg : wu;
      op = (v < 4096) ? wgb : wub;
      int w = v & 4095;
      R = D_DIM; C = E_NUM * H_DIM;
      c0 = (w & 511) * 32; r0 = (w >> 9) * 64;
    } else {
      in = wd; op = wdb;
      int w = v - 8192;
      R = H_DIM; C = D_DIM;
      c0 = (w & 15) * 32; r0 = (w >> 4) * 64;
    }
    // load phase: float4 per lane; covers rows 0..63, cols 0..31
    int cx = tid & 7, ry = tid >> 3;  // cx: float4-col 0..7, ry: row 0..31
#pragma unroll
    for (int p = 0; p < 2; ++p) {
      int row = ry + 32 * p;
      float4 vv = *(const float4*)&in[(size_t)(r0 + row) * C + c0 + cx * 4];
      tbuf[row][cx * 4 + 0] = vv.x;
      tbuf[row][cx * 4 + 1] = vv.y;
      tbuf[row][cx * 4 + 2] = vv.z;
      tbuf[row][cx * 4 + 3] = vv.w;
    }
    __syncthreads();
    // pack phase: proven round-0 code (unchanged)
    int tx = tid & 31, ty = tid >> 5;
#pragma unroll
    for (int i = 0; i < 4; ++i) {
      int cl = ty + 8 * i;
      unsigned lo = (unsigned short)f2bs(tbuf[2 * tx][cl]);
      unsigned hi = (unsigned short)f2bs(tbuf[2 * tx + 1][cl]);
      ((int*)op)[(((size_t)(c0 + cl) * R) + r0) / 2 + tx] = (int)(lo | (hi << 16));
    }
    return;
  }

  // ---- router part: 16 tokens, 16 lanes per token ----
  __shared__ float wr_t[E_NUM * D_DIM];  // [e][d], 16 KB
  __shared__ int h_cnt[E_NUM];
  __shared__ float psh[E_NUM];
  int rb = u;
  for (int i = tid; i < D_DIM * E_NUM; i += 256)
    wr_t[(i & 7) * D_DIM + (i >> 3)] = wr[i];  // wr is [d][e]
  if (tid < E_NUM) { h_cnt[tid] = 0; psh[tid] = 0.f; }
  __syncthreads();

  int r = tid >> 4, pp = tid & 15;
  int t = rb * 16 + r;
  const float* xr0 = x + (size_t)t * D_DIM;
  short* xw0 = xb + (size_t)t * D_DIM;
  float acc[8] = {0, 0, 0, 0, 0, 0, 0, 0};
#pragma unroll
  for (int j = 0; j < 8; ++j) {
    int d = j * 64 + pp * 4;  // 16 lanes cover 64 consecutive floats
    float4 xv = *(const float4*)(xr0 + d);
    short4 o;
    o.x = f2bs(xv.x); o.y = f2bs(xv.y); o.z = f2bs(xv.z); o.w = f2bs(xv.w);
    *(short4*)(xw0 + d) = o;
#pragma unroll
    for (int e = 0; e < 8; ++e) {
      float4 w = *(const float4*)&wr_t[e * D_DIM + d];
      acc[e] += xv.x * w.x + xv.y * w.y + xv.z * w.z + xv.w * w.w;
    }
  }
#pragma unroll
  for (int e = 0; e < 8; ++e) {
    acc[e] += __shfl_xor(acc[e], 1);
    acc[e] += __shfl_xor(acc[e], 2);
    acc[e] += __shfl_xor(acc[e], 4);
    acc[e] += __shfl_xor(acc[e], 8);
  }

  if (pp == 0) {
    float m = acc[0];
#pragma unroll
    for (int e = 1; e < 8; ++e) m = fmaxf(m, acc[e]);
    float p[8], s = 0.f;
#pragma unroll
    for (int e = 0; e < 8; ++e) { p[e] = expf(acc[e] - m); s += p[e]; }
    float inv = 1.f / s;
#pragma unroll
    for (int e = 0; e < 8; ++e) {
      p[e] *= inv;
      atomicAdd(&psh[e], p[e]);  // LDS scope
    }
    int i0 = 0;
#pragma unroll
    for (int e = 1; e < 8; ++e) if (p[e] > p[i0]) i0 = e;
    int i1 = (i0 == 0) ? 1 : 0;
#pragma unroll
    for (int e = 0; e < 8; ++e) if (e != i0 && p[e] > p[i1]) i1 = e;
    float ps = p[i0] + p[i1] + 1e-10f;
    float q0 = p[i0] / ps, q1 = p[i1] / ps;
    int l0 = atomicAdd(&h_cnt[i0], 1);  // LDS scope
    int l1 = atomicAdd(&h_cnt[i1], 1);
    tok_bkt[i0 * (RB_NUM * 16) + rb * 16 + l0] = t * 2 + 0;
    p_bkt[i0 * (RB_NUM * 16) + rb * 16 + l0] = q0;
    tok_bkt[i1 * (RB_NUM * 16) + rb * 16 + l1] = t * 2 + 1;
    p_bkt[i1 * (RB_NUM * 16) + rb * 16 + l1] = q1;
  }
  __syncthreads();
  if (tid < E_NUM) {
    cnt_blk[rb * 8 + tid] = h_cnt[tid];   // plain stores, fully owned
    psum_blk[rb * 8 + tid] = psh[tid];
  }
}

// ---------- route pack: 128 blocks = 8 experts x 16 rb-chunks ----------
__global__ void __launch_bounds__(256) route_pack_kernel(
    const int* __restrict__ cnt_blk, const int* __restrict__ tok_bkt,
    const float* __restrict__ p_bkt, int* __restrict__ dense_tok,
    float* __restrict__ dense_p, int* __restrict__ n_tot) {
  int e = blockIdx.x >> 4;
  int chunk = blockIdx.x & 15;
  int tid = threadIdx.x, lane = tid & 63, wid = tid >> 6;
  __shared__ int wsum[4];
  __shared__ int s_excl[16];
  __shared__ int s_cnt[16];
  int c = cnt_blk[tid * 8 + e];
  int inc = c;
#pragma unroll
  for (int ofs = 1; ofs < 64; ofs <<= 1) {
    int v = __shfl_up(inc, ofs);
    if (lane >= ofs) inc += v;
  }
  if (lane == 63) wsum[wid] = inc;
  __syncthreads();
  int pre = 0;
#pragma unroll
  for (int w = 0; w < 4; ++w) pre += (w < wid) ? wsum[w] : 0;
  int excl = inc + pre - c;
  if ((tid >> 4) == chunk) {
    s_excl[tid & 15] = excl;
    s_cnt[tid & 15] = c;
  }
  if (chunk == 0 && tid == 255) n_tot[e] = inc + pre;
  __syncthreads();
  int rbl = tid >> 4, i = tid & 15;
  int rb = chunk * 16 + rbl;
  if (i < s_cnt[rbl]) {
    int src = e * (RB_NUM * 16) + rb * 16 + i;
    int dst = e * N_TOK + s_excl[rbl] + i;
    dense_tok[dst] = tok_bkt[src];
    dense_p[dst] = p_bkt[src];
  }
}

// ---------- grouped gate/up GEMM (256 tok x 64 h tile, G+U fused) ----------
// round-0 proven structure: single-buffered LDS, 2 barriers/K-step, 3 blocks/CU.
// metadata from precomputed dense list (no per-block scan / binary search).
__global__ void __launch_bounds__(256, 2) moe_gateup_kernel(
    const short* __restrict__ xb, const short* __restrict__ wg,
    const short* __restrict__ wu, const int* __restrict__ dense_tok,
    const float* __restrict__ dense_p, const int* __restrict__ n_tot,
    const float* __restrict__ psum_blk, short* __restrict__ act,
    float* __restrict__ out_loss) {
  int e = blockIdx.z;
  int tid = threadIdx.x;

  if (e == 8) {  // load-balance loss
    if (blockIdx.x || blockIdx.y) return;
    __shared__ float sums[8];
    if (tid < 8) sums[tid] = 0.f;
    __syncthreads();
#pragma unroll
    for (int ee = 0; ee < 8; ++ee)
      atomicAdd(&sums[ee], psum_blk[tid * 8 + ee]);
    __syncthreads();
    if (tid == 0) {
      float lb = 0.f;
#pragma unroll
      for (int ee = 0; ee < 8; ++ee) {
        float pe = sums[ee] / (float)N_TOK;
        lb += pe * logf(pe * 8.f + 1e-10f);
      }
      out_loss[0] = 8.f * lb;
    }
    return;
  }

  int n_e = n_tot[e];
  int rt = blockIdx.y;
  if (rt * 256 >= n_e) return;  // uniform early exit, one scalar load
  int h0 = blockIdx.x * 64;

  __shared__ __align__(16) short As[256 * 64];   // 32 KB
  __shared__ __align__(16) short Bgs[64 * 64];   // 8 KB
  __shared__ __align__(16) short Bus[64 * 64];   // 8 KB
  __shared__ int s_row[256];
  __shared__ float s_pr[256];

  int lane = tid & 63, wid = tid >> 6;

  {
    int r = rt * 256 + tid;
    int srow = -1;
    float spr = 0.f;
    if (r < n_e) {
      srow = dense_tok[e * N_TOK + r];
      spr = dense_p[e * N_TOK + r];
    }
    s_row[tid] = srow;
    s_pr[tid] = spr;
  }
  __syncthreads();

  int cg = (lane & 7) ^ (lane >> 3);  // swizzled global chunk for this lane
  const short* baseA[8];
  const short* baseB[4];
#pragma unroll
  for (int jj = 0; jj < 8; ++jj) {
    int r = wid * 64 + jj * 8 + (lane >> 3);
    int row = s_row[r];
    int t = (row < 0) ? 0 : (row >> 1);
    baseA[jj] = xb + (size_t)t * D_DIM + cg * 8;
  }
  short* ldsB;
  {
    const short* wB = ((wid & 2) ? wu : wg) + (size_t)e * H_DIM * D_DIM;
    int rb = (wid & 1) * 32;
    ldsB = ((wid & 2) ? Bus : Bgs) + rb * 64;
#pragma unroll
    for (int jj = 0; jj < 4; ++jj) {
      int h = h0 + rb + jj * 8 + (lane >> 3);
      baseB[jj] = wB + (size_t)h * D_DIM + cg * 8;
    }
  }

  int ml = lane & 15, quad = lane >> 4;
  int m0w = wid * 64;
  f32x4 accG[4][4], accU[4][4];
#pragma unroll
  for (int mf = 0; mf < 4; ++mf)
#pragma unroll
    for (int nf = 0; nf < 4; ++nf) {
      accG[mf][nf] = (f32x4){0, 0, 0, 0};
      accU[mf][nf] = (f32x4){0, 0, 0, 0};
    }

  for (int kt = 0; kt < D_DIM / 64; ++kt) {
    int kb = kt * 64;
#pragma unroll
    for (int jj = 0; jj < 8; ++jj)
      llds16(baseA[jj] + kb, As + wid * 4096 + jj * 512);
#pragma unroll
    for (int jj = 0; jj < 4; ++jj)
      llds16(baseB[jj] + kb, ldsB + jj * 512);
    __syncthreads();
#pragma unroll
    for (int ks = 0; ks < 2; ++ks) {
      int cs = ((quad + ks * 4) ^ (ml & 7)) * 8;
      short8 a[4], bg[4], bu[4];
#pragma unroll
      for (int mf = 0; mf < 4; ++mf)
        a[mf] = *(const short8*)&As[(m0w + mf * 16 + ml) * 64 + cs];
#pragma unroll
      for (int nf = 0; nf < 4; ++nf) {
        bg[nf] = *(const short8*)&Bgs[(nf * 16 + ml) * 64 + cs];
        bu[nf] = *(const short8*)&Bus[(nf * 16 + ml) * 64 + cs];
      }
#pragma unroll
      for (int mf = 0; mf < 4; ++mf)
#pragma unroll
        for (int nf = 0; nf < 4; ++nf) {
          accG[mf][nf] = __builtin_amdgcn_mfma_f32_16x16x32_bf16(a[mf], bg[nf], accG[mf][nf], 0, 0, 0);
          accU[mf][nf] = __builtin_amdgcn_mfma_f32_16x16x32_bf16(a[mf], bu[nf], accU[mf][nf], 0, 0, 0);
        }
    }
    __syncthreads();
  }

#pragma unroll
  for (int mf = 0; mf < 4; ++mf)
#pragma unroll
    for (int r = 0; r < 4; ++r) {
      int rl = m0w + mf * 16 + quad * 4 + r;
      int arow = s_row[rl];
      if (arow >= 0) {
        float pr = s_pr[rl];
#pragma unroll
        for (int nf = 0; nf < 4; ++nf) {
          float g = accG[mf][nf][r], u = accU[mf][nf][r];
          float val = pr * (g / (1.f + __expf(-g))) * u;
          act[(size_t)arow * H_DIM + h0 + nf * 16 + ml] = f2bs(val);
        }
      }
    }
}

// ---------- down GEMM: partial[ksb][t][d] = act-slice @ wd ----------
// 64tok x 256d tile (act read only 2x total, was 4x), Ksplit=4 over blockIdx.z.
// 4 waves: each owns 64tok x 64d strip; both slots accumulate into one acc
// with the B fragment reused in-register. 48 KB LDS -> 3 blocks/CU.
__global__ void __launch_bounds__(256, 3) down_kernel(
    const short* __restrict__ act, const short* __restrict__ wd,
    float* __restrict__ partial) {
  __shared__ __align__(16) short As0[64 * 64];   // 8 KB (slot 0)
  __shared__ __align__(16) short As1[64 * 64];   // 8 KB (slot 1)
  __shared__ __align__(16) short Bs[256 * 64];   // 32 KB
  int d0 = blockIdx.x * 256;
  int t0 = blockIdx.y * 64;
  int ksb = blockIdx.z;  // h-chunks [ksb*8, ksb*8+8)
  int tid = threadIdx.x, lane = tid & 63, wid = tid >> 6;
  int cg = (lane & 7) ^ (lane >> 3);

  // staging: waves 0-1 stage As0 rows [(wid&1)*32..+32), waves 2-3 same for As1;
  // every wave stages its own B strip [wid*64..+64).  12 llds16/wave per j.
  const short* baseA[4];
  const short* baseB[8];
  int slot = wid >> 1;
  int arow0 = (wid & 1) * 32;
#pragma unroll
  for (int jj = 0; jj < 4; ++jj) {
    int r = arow0 + jj * 8 + (lane >> 3);
    baseA[jj] = act + (size_t)(2 * (t0 + r) + slot) * H_DIM + cg * 8;
  }
#pragma unroll
  for (int jj = 0; jj < 8; ++jj) {
    int d = d0 + wid * 64 + jj * 8 + (lane >> 3);
    baseB[jj] = wd + (size_t)d * H_DIM + cg * 8;
  }
  short* ldsA = (slot ? As1 : As0) + arow0 * 64;

  int ml = lane & 15, quad = lane >> 4;
  int n0w = wid * 64;
  f32x4 acc[4][4];
#pragma unroll
  for (int mf = 0; mf < 4; ++mf)
#pragma unroll
    for (int nf = 0; nf < 4; ++nf) acc[mf][nf] = (f32x4){0, 0, 0, 0};

  for (int j = 0; j < 8; ++j) {
    int hb = (ksb * 8 + j) * 64;
#pragma unroll
    for (int jj = 0; jj < 4; ++jj)
      llds16(baseA[jj] + hb, ldsA + jj * 512);
#pragma unroll
    for (int jj = 0; jj < 8; ++jj)
      llds16(baseB[jj] + hb, Bs + wid * 4096 + jj * 512);
    __syncthreads();
#pragma unroll
    for (int ks = 0; ks < 2; ++ks) {
      int cs = ((quad + ks * 4) ^ (ml & 7)) * 8;
      short8 a0[4], a1[4], b[4];
#pragma unroll
      for (int mf = 0; mf < 4; ++mf) {
        a0[mf] = *(const short8*)&As0[(mf * 16 + ml) * 64 + cs];
        a1[mf] = *(const short8*)&As1[(mf * 16 + ml) * 64 + cs];
      }
#pragma unroll
      for (int nf = 0; nf < 4; ++nf)
        b[nf] = *(const short8*)&Bs[(n0w + nf * 16 + ml) * 64 + cs];
#pragma unroll
      for (int mf = 0; mf < 4; ++mf)
#pragma unroll
        for (int nf = 0; nf < 4; ++nf) {
          acc[mf][nf] = __builtin_amdgcn_mfma_f32_16x16x32_bf16(a0[mf], b[nf], acc[mf][nf], 0, 0, 0);
          acc[mf][nf] = __builtin_amdgcn_mfma_f32_16x16x32_bf16(a1[mf], b[nf], acc[mf][nf], 0, 0, 0);
        }
    }
    __syncthreads();
  }

  float* pout = partial + (size_t)ksb * N_TOK * D_DIM;
#pragma unroll
  for (int mf = 0; mf < 4; ++mf)
#pragma unroll
    for (int r = 0; r < 4; ++r) {
      int t = t0 + mf * 16 + quad * 4 + r;
#pragma unroll
      for (int nf = 0; nf < 4; ++nf)
        pout[(size_t)t * D_DIM + d0 + n0w + nf * 16 + ml] = acc[mf][nf][r];
    }
}

// ---------- split-K reduce: out = sum of 4 partials ----------
__global__ void __launch_bounds__(256) reduce_kernel(
    const float* __restrict__ partial, float* __restrict__ out) {
  int i = blockIdx.x * 256 + threadIdx.x;  // float4 index
  const int Q = N_TOK * D_DIM / 4;
  const float4* p = (const float4*)partial;
  float4 a = p[i], b = p[i + Q], c = p[i + 2 * Q], d = p[i + 3 * Q];
  float4 r = {a.x + b.x + c.x + d.x, a.y + b.y + c.y + d.y,
              a.z + b.z + c.z + d.z, a.w + b.w + c.w + d.w};
  ((float4*)out)[i] = r;
}

extern "C" void kernel_launch(void* const* d_in, const int* in_sizes, int n_in,
                              void* d_out, int out_size, void* d_ws, size_t ws_size,
                              hipStream_t stream) {
  const float* x = (const float*)d_in[0];
  const float* wr = (const float*)d_in[1];
  const float* wg = (const float*)d_in[2];
  const float* wu = (const float*)d_in[3];
  const float* wd = (const float*)d_in[4];
  float* out = (float*)d_out;

  char* ws = (char*)d_ws;
  size_t off = 0;
  auto alloc = [&](size_t bytes) {
    char* p = ws + off;
    off += (bytes + 255) & ~(size_t)255;
    return p;
  };
  short* xb = (short*)alloc((size_t)N_TOK * D_DIM * 2);
  short* wgb = (short*)alloc((size_t)E_NUM * H_DIM * D_DIM * 2);  // [e*H+h][d]
  short* wub = (short*)alloc((size_t)E_NUM * H_DIM * D_DIM * 2);
  short* wdb = (short*)alloc((size_t)D_DIM * H_DIM * 2);          // [d][h]
  short* act = (short*)alloc((size_t)N_TOK * 2 * H_DIM * 2);      // [2t+slot][H]
  float* partial = (float*)alloc((size_t)4 * N_TOK * D_DIM * 4);  // split-K partials
  int* cnt_blk = (int*)alloc((size_t)RB_NUM * E_NUM * 4);
  int* tok_bkt = (int*)alloc((size_t)E_NUM * RB_NUM * 16 * 4);
  float* p_bkt = (float*)alloc((size_t)E_NUM * RB_NUM * 16 * 4);
  float* psum_blk = (float*)alloc((size_t)RB_NUM * E_NUM * 4);
  int* dense_tok = (int*)alloc((size_t)E_NUM * N_TOK * 4);
  float* dense_p = (float*)alloc((size_t)E_NUM * N_TOK * 4);
  int* n_tot = (int*)alloc((size_t)E_NUM * 4);

  prep_router_kernel<<<RB_NUM + TP_NUM, 256, 0, stream>>>(
      wg, wu, wd, x, wr, wgb, wub, wdb, xb, cnt_blk, tok_bkt, p_bkt, psum_blk);
  route_pack_kernel<<<E_NUM * 16, 256, 0, stream>>>(
      cnt_blk, tok_bkt, p_bkt, dense_tok, dense_p, n_tot);
  moe_gateup_kernel<<<dim3(H_DIM / 64, N_TOK / 256, E_NUM + 1), 256, 0, stream>>>(
      xb, wgb, wub, dense_tok, dense_p, n_tot, psum_blk, act,
      out + (size_t)N_TOK * D_DIM);
  down_kernel<<<dim3(D_DIM / 256, N_TOK / 64, 4), 256, 0, stream>>>(
      act, wdb, partial);
  reduce_kernel<<<N_TOK * D_DIM / 4 / 256, 256, 0, stream>>>(partial, out);
}